// Round 22
// baseline (262.501 us; speedup 1.0000x reference)
//
#include <hip/hip_runtime.h>

#define N_NODES 32768
#define G_GRAPHS 1024
#define D_DIM 512
#define H_DIM 768
#define B_BR 4
#define GHD 64
#define NHD 3

// output layout (f32, concatenated flat)
#define NH_OFF (G_GRAPHS * GHD)
#define GV_OFF (G_GRAPHS * GHD + N_NODES * NHD)
#define NV_OFF (2 * G_GRAPHS * GHD + N_NODES * NHD)

typedef unsigned short ushort_t;
typedef __attribute__((ext_vector_type(8))) short short8;
typedef __attribute__((ext_vector_type(4))) float f32x4;
typedef __attribute__((ext_vector_type(4))) ushort_t ushort4_t;

__device__ __forceinline__ ushort_t rne_bf16(float v) {
  unsigned bits = __float_as_uint(v);
  return (ushort_t)((bits + 0x7fffu + ((bits >> 16) & 1u)) >> 16);
}

// ---------------------------------------------------------------------------
// fused segment-bounds + 4-wave branch scan. One block, 1024 threads.
// ---------------------------------------------------------------------------
__global__ __launch_bounds__(1024) void segscan_kernel(
    const int* __restrict__ batch, const int* __restrict__ dsname,
    int* __restrict__ gstart, int* __restrict__ goff, int* __restrict__ glist,
    int* __restrict__ cnt, int* __restrict__ gcnt, int* __restrict__ pbase) {
  __shared__ int sg[G_GRAPHS + 1];
  __shared__ int scnt[4], sgcnt[4];
  const int tid = threadIdx.x;
  {
    int g = tid;
    int lo = 0, hi = N_NODES;
    while (lo < hi) { int mid = (lo + hi) >> 1; if (batch[mid] < g) lo = mid + 1; else hi = mid; }
    sg[g] = lo; gstart[g] = lo;
    if (tid == 0) { sg[G_GRAPHS] = N_NODES; gstart[G_GRAPHS] = N_NODES; }
  }
  __syncthreads();
  if (tid < 256) {
    const int lane = tid & 63;
    const int b = tid >> 6;
    int run_n = 0, run_g = 0;
    for (int c = 0; c < G_GRAPHS / 64; ++c) {
      int g = c * 64 + lane;
      int mine = (dsname[g] == b) ? 1 : 0;
      int len = mine ? (sg[g + 1] - sg[g]) : 0;
      int sl = len, so = mine;
#pragma unroll
      for (int off = 1; off < 64; off <<= 1) {
        int tl = __shfl_up(sl, off);
        int to = __shfl_up(so, off);
        if (lane >= off) { sl += tl; so += to; }
      }
      if (mine) {
        goff[g] = run_n + sl - len;
        glist[b * G_GRAPHS + run_g + so - 1] = g;
      }
      run_n += __shfl(sl, 63);
      run_g += __shfl(so, 63);
    }
    if (lane == 0) { scnt[b] = run_n; sgcnt[b] = run_g; }
  }
  __syncthreads();
  if (tid == 0) {
    int p = 0;
    for (int b2 = 0; b2 < 4; ++b2) {
      cnt[b2] = scnt[b2];
      gcnt[b2] = sgcnt[b2];
      pbase[b2] = p;
      p += (scnt[b2] + 63) & ~63;
    }
  }
}

// ---------------------------------------------------------------------------
// prep kernel (weights + lists only): bids 0..255 Wn1, 256..639 WG1,
// 640..643 WG2, 644..647 W2T, 648..775 lists
// ---------------------------------------------------------------------------
__global__ __launch_bounds__(256) void prep_kernel(
    const int* __restrict__ gstart, const int* __restrict__ goff,
    const int* __restrict__ dsname, int* __restrict__ lists,
    const float* __restrict__ Wn1, ushort_t* __restrict__ WPh,
    const float* __restrict__ Wg1, ushort_t* __restrict__ WG1,
    const float* __restrict__ Wgh, ushort_t* __restrict__ WG2,
    const float* __restrict__ Wn2, ushort_t* __restrict__ W2T) {
  __shared__ float Ws[64][65];
  const int bid = blockIdx.x;
  const int tid = threadIdx.x;

  if (bid < 256) {  // Wn1 -> WPh
    int b = bid >> 6, t = bid & 63;
    int kt = t >> 3, nt = t & 7;
    const float* W = Wn1 + (size_t)b * D_DIM * D_DIM;
    for (int i = tid; i < 64 * 64; i += 256) {
      int k = i >> 6, n = i & 63;
      Ws[k][n] = W[(size_t)(kt * 64 + k) * D_DIM + nt * 64 + n];
    }
    __syncthreads();
    for (int i = tid; i < 64 * 8; i += 256) {
      int n = i >> 3, kq8 = i & 7;
      short8 sh;
#pragma unroll
      for (int j = 0; j < 8; ++j) sh[j] = (short)rne_bf16(Ws[kq8 * 8 + j][n]);
      int gn = nt * 64 + n, gk0 = kt * 64 + kq8 * 8;
      int n16 = gn >> 4, l15 = gn & 15;
      int ks = gk0 >> 5, lq = (gk0 >> 3) & 3;
      size_t off = ((((size_t)b * 32 + n16) * 16 + ks) * 64 + lq * 16 + l15) * 8;
      *reinterpret_cast<short8*>(WPh + off) = sh;
    }
  } else if (bid < 640) {  // Wg_shared -> WG1
    int l2 = bid - 256;
    int b = l2 / 96, t = l2 % 96;
    int kt = t / 12, nt = t % 12;
    const float* W = Wg1 + (size_t)b * D_DIM * H_DIM;
    for (int i = tid; i < 64 * 64; i += 256) {
      int k = i >> 6, n = i & 63;
      Ws[k][n] = W[(size_t)(kt * 64 + k) * H_DIM + nt * 64 + n];
    }
    __syncthreads();
    for (int i = tid; i < 64 * 8; i += 256) {
      int n = i >> 3, kq8 = i & 7;
      short8 sh;
#pragma unroll
      for (int j = 0; j < 8; ++j) sh[j] = (short)rne_bf16(Ws[kq8 * 8 + j][n]);
      int gn = nt * 64 + n, gk0 = kt * 64 + kq8 * 8;
      int n16 = gn >> 4, l15 = gn & 15;
      int ks = gk0 >> 5, lq = (gk0 >> 3) & 3;
      size_t off = ((((size_t)b * 48 + n16) * 16 + ks) * 64 + lq * 16 + l15) * 8;
      *reinterpret_cast<short8*>(WG1 + off) = sh;
    }
  } else if (bid < 644) {  // Wg_head -> WG2
    int b = bid - 640;
    const float* W = Wgh + (size_t)b * H_DIM * 2 * GHD;
    for (int i = tid; i < 8 * 24 * 64; i += 256) {
      int n16 = i / (24 * 64);
      int rem = i % (24 * 64);
      int ks = rem / 64, lane = rem % 64;
      int l15 = lane & 15, lq = lane >> 4;
      int o = n16 * 16 + l15;
      short8 sv;
#pragma unroll
      for (int j = 0; j < 8; ++j) {
        int k = ks * 32 + lq * 8 + j;
        sv[j] = (short)rne_bf16(W[(size_t)k * 128 + o]);
      }
      *reinterpret_cast<short8*>(WG2 + (size_t)i * 8 + (size_t)b * (8 * 24 * 64 * 8)) = sv;
    }
  } else if (bid < 648) {  // Wn2 -> W2T
    int b = bid - 644;
    for (int i = tid; i < 16 * D_DIM; i += 256) {
      int o = i & 15, c = i >> 4;
      float v = (o < 6) ? Wn2[(size_t)b * D_DIM * 6 + c * 6 + o] : 0.0f;
      W2T[(size_t)b * 16 * D_DIM + o * D_DIM + c] = rne_bf16(v);
    }
  } else {  // lists emit: 8 graphs per block
    int blk = bid - 648;
#pragma unroll
    for (int j = 0; j < 8; ++j) {
      int g = blk * 8 + j;
      int start = gstart[g];
      int len = gstart[g + 1] - start;
      int b = dsname[g];
      int og = goff[g];
      for (int i = tid; i < len; i += 256) lists[b * N_NODES + og + i] = start + i;
    }
  }
}

// ---------------------------------------------------------------------------
// mega kernel: [0,1024) pool blocks (1 graph each -> xgb, then release flag);
// [1024,1600) node GEMM (XCD-pinned, 2-buffer B DMA pipeline);
// [1600,1728) graph MLP (XCD-pinned; acquire-spins on pool flag).
// Deadlock-free: 128 graph blocks < 256 CUs; pools wait on nothing.
// ---------------------------------------------------------------------------
#define NBM 64
#define POOL_BLOCKS 1024
#define NODE_BLOCKS 576
#define GRAPH_BLOCKS 128

__global__ __launch_bounds__(512, 2) void mega_kernel(
    const float* __restrict__ x,
    const ushort_t* __restrict__ WPh,
    const float* __restrict__ bn1,
    const ushort_t* __restrict__ W2T, const float* __restrict__ bn2,
    const int* __restrict__ cnt, const int* __restrict__ pbase,
    const int* __restrict__ lists, const int* __restrict__ gstart,
    ushort_t* __restrict__ xgb, int* __restrict__ poolflag,
    const ushort_t* __restrict__ WG1, const float* __restrict__ bg_shared,
    const ushort_t* __restrict__ WG2, const float* __restrict__ bg_head,
    const int* __restrict__ gcnt, const int* __restrict__ glist,
    float* __restrict__ out) {
  __shared__ __align__(16) char smem[131072];
  __shared__ int idxbuf[64];

  const int bid = blockIdx.x;
  const int tid = threadIdx.x;
  const int lane = tid & 63;
  const int w = tid >> 6;
  const int l15 = lane & 15;
  const int lq = lane >> 4;

  if (bid < POOL_BLOCKS) {
    // ---------------- pool: 1 graph per block (8 row-stripes) ----------------
    const int rl = tid >> 6;
    const int cs = tid & 63;
    const int g = bid;
    const int start = gstart[g];
    const int len = gstart[g + 1] - start;
    float s0 = 0.f, s1 = 0.f, s2 = 0.f, s3 = 0.f;
    float s4 = 0.f, s5 = 0.f, s6 = 0.f, s7 = 0.f;
    for (int i = rl; i < len; i += 8) {
      const float* sp = x + (size_t)(start + i) * D_DIM + cs * 8;
      float4 v0 = *reinterpret_cast<const float4*>(sp);
      float4 v1 = *reinterpret_cast<const float4*>(sp + 4);
      s0 += v0.x; s1 += v0.y; s2 += v0.z; s3 += v0.w;
      s4 += v1.x; s5 += v1.y; s6 += v1.z; s7 += v1.w;
    }
    float* red = (float*)smem;  // [8][64][8] f32 = 16 KB
    float* rr = red + (rl * 64 + cs) * 8;
    rr[0] = s0; rr[1] = s1; rr[2] = s2; rr[3] = s3;
    rr[4] = s4; rr[5] = s5; rr[6] = s6; rr[7] = s7;
    __syncthreads();
    if (rl == 0) {
      float inv = (len > 0) ? 1.0f / (float)len : 0.0f;
      short8 h;
#pragma unroll
      for (int k = 0; k < 8; ++k) {
        float tot = 0.f;
#pragma unroll
        for (int p = 0; p < 8; ++p) tot += red[(p * 64 + cs) * 8 + k];
        h[k] = (short)rne_bf16(tot * inv);
      }
      *reinterpret_cast<short8*>(xgb + (size_t)g * D_DIM + cs * 8) = h;
    }
    __threadfence();   // make xgb writes device-visible
    __syncthreads();
    if (tid == 0)
      __hip_atomic_fetch_add(poolflag, 1, __ATOMIC_RELEASE, __HIP_MEMORY_SCOPE_AGENT);
  } else if (bid < POOL_BLOCKS + NODE_BLOCKS) {
    // ---------------- node path (XCD-pinned, B-pipelined) ----------------
    const int nb = bid - POOL_BLOCKS;               // 1024%8==0 -> parity kept
    const int b = (nb & 7) >> 1;                    // XCD pair -> branch
    const int tile = ((nb >> 3) << 1) | (nb & 1);   // within-branch tile
    const int count = cnt[b];
    const int base = tile * NBM;
    if (base >= count) return;

    ushort_t* Ah = (ushort_t*)smem;
    if (tid < NBM) {
      int r = base + tid;
      idxbuf[tid] = (r < count) ? lists[b * N_NODES + r] : lists[b * N_NODES];
    }
    __syncthreads();  // idxbuf visible

    // stage A: gather rows from x, convert f32->bf16, swizzled ds_write.
#pragma unroll
    for (int it = 0; it < 8; ++it) {
      int u = it * 512 + tid;
      int r = u >> 6, cp = u & 63;
      const float* sp = x + (size_t)idxbuf[r] * D_DIM + cp * 8;
      float4 v0 = *reinterpret_cast<const float4*>(sp);
      float4 v1 = *reinterpret_cast<const float4*>(sp + 4);
      short8 h;
      h[0] = (short)rne_bf16(v0.x); h[1] = (short)rne_bf16(v0.y);
      h[2] = (short)rne_bf16(v0.z); h[3] = (short)rne_bf16(v0.w);
      h[4] = (short)rne_bf16(v1.x); h[5] = (short)rne_bf16(v1.y);
      h[6] = (short)rne_bf16(v1.z); h[7] = (short)rne_bf16(v1.w);
      *reinterpret_cast<short8*>((char*)Ah + r * 1024 + ((cp ^ (r & 7)) << 4)) = h;
    }
    __syncthreads();

    const ushort_t* __restrict__ wph =
        WPh + (((size_t)b * 32 + w * 4) * 16) * 512 + (size_t)lane * 8;
    ushort_t* Bl = (ushort_t*)(smem + 65536 + w * 8192);  // wave-private 2x4KB

    // prologue: issue ks=0 into buf0
#pragma unroll
    for (int ct = 0; ct < 4; ++ct) {
      __builtin_amdgcn_global_load_lds(
          (const __attribute__((address_space(1))) void*)(wph + (size_t)(ct * 16) * 512),
          (__attribute__((address_space(3))) void*)(Bl + ct * 512),
          16, 0, 0);
    }

    f32x4 acc[4][4];
#pragma unroll
    for (int i = 0; i < 4; ++i)
#pragma unroll
      for (int j = 0; j < 4; ++j) acc[i][j] = (f32x4){0.f, 0.f, 0.f, 0.f};

#pragma unroll
    for (int ks = 0; ks < 16; ++ks) {
      const int nks = (ks + 1) & 15;
      ushort_t* Bnx = Bl + ((ks + 1) & 1) * 2048;
#pragma unroll
      for (int ct = 0; ct < 4; ++ct) {
        __builtin_amdgcn_global_load_lds(
            (const __attribute__((address_space(1))) void*)(wph + (size_t)(ct * 16 + nks) * 512),
            (__attribute__((address_space(3))) void*)(Bnx + ct * 512),
            16, 0, 0);
      }
      asm volatile("s_waitcnt vmcnt(4)" ::: "memory");
      __builtin_amdgcn_sched_barrier(0);
      const ushort_t* Bc = Bl + (ks & 1) * 2048;
      short8 ah[4], bh[4];
#pragma unroll
      for (int rt = 0; rt < 4; ++rt) {
        int R = rt * 16 + l15;
        int byteoff = R * 1024 + ((ks * 64 + lq * 16) ^ ((R & 7) << 4));
        ah[rt] = *reinterpret_cast<const short8*>((const char*)Ah + byteoff);
      }
#pragma unroll
      for (int ct = 0; ct < 4; ++ct)
        bh[ct] = *reinterpret_cast<const short8*>(Bc + ct * 512 + lane * 8);
#pragma unroll
      for (int ct = 0; ct < 4; ++ct) {
#pragma unroll
        for (int rt = 0; rt < 4; ++rt) {
          acc[rt][ct] = __builtin_amdgcn_mfma_f32_16x16x32_bf16(ah[rt], bh[ct], acc[rt][ct], 0, 0, 0);
        }
      }
    }

    __syncthreads();
    ushort_t* hn = Ah;
#pragma unroll
    for (int ct = 0; ct < 4; ++ct) {
      int n = w * 64 + ct * 16 + l15;
      float bias = bn1[b * D_DIM + n];
#pragma unroll
      for (int rt = 0; rt < 4; ++rt) {
#pragma unroll
        for (int j = 0; j < 4; ++j) {
          int row = rt * 16 + lq * 4 + j;
          float v = fmaxf(acc[rt][ct][j] + bias, 0.0f);
          int byteoff = row * 1024 + ((n * 2) ^ ((row & 7) << 4));
          *reinterpret_cast<ushort_t*>((char*)hn + byteoff) = rne_bf16(v);
        }
      }
    }
    __syncthreads();

    if (w < 4) {
      f32x4 acc2 = (f32x4){0.f, 0.f, 0.f, 0.f};
      const ushort_t* __restrict__ w2 =
          W2T + (size_t)b * (16 * 512) + (size_t)l15 * 512 + lq * 8;
      const int R = w * 16 + l15;
#pragma unroll
      for (int ks = 0; ks < 16; ++ks) {
        int byteoff = R * 1024 + ((ks * 64 + lq * 16) ^ ((R & 7) << 4));
        short8 a2 = *reinterpret_cast<const short8*>((const char*)hn + byteoff);
        short8 b2 = *reinterpret_cast<const short8*>(w2 + ks * 32);
        acc2 = __builtin_amdgcn_mfma_f32_16x16x32_bf16(a2, b2, acc2, 0, 0, 0);
      }
      int o = l15;
      if (o < 6) {
        float bo = bn2[b * 6 + o];
#pragma unroll
        for (int j = 0; j < 4; ++j) {
          int r = w * 16 + lq * 4 + j;
          if (base + r < count) {
            int n = idxbuf[r];
            float v = acc2[j] + bo;
            if (o < NHD) out[NH_OFF + n * NHD + o] = v;
            else out[NV_OFF + n * NHD + (o - NHD)] = v * v;
          }
        }
      }
    }
  } else {
    // ---------------- graph path (XCD-pinned, waits on pool) ----------------
    const int gb = bid - POOL_BLOCKS - NODE_BLOCKS;  // 1600%8==0 -> parity kept
    const int b = (gb & 7) >> 1;                     // XCD pair -> branch
    const int tile = ((gb >> 3) << 1) | (gb & 1);    // 0..31
    const int gc = gcnt[b];
    const int base = tile * 32;
    if (base >= gc) return;

    if (tid == 0) {
      while (__hip_atomic_load(poolflag, __ATOMIC_ACQUIRE,
                               __HIP_MEMORY_SCOPE_AGENT) < G_GRAPHS) {}
    }
    __syncthreads();

    ushort_t* Ag = (ushort_t*)smem;       // 32 x 512 bf16, swizzled (32 KB)
    if (tid < 32) {
      int r = base + tid;
      idxbuf[tid] = (r < gc) ? glist[b * G_GRAPHS + r] : glist[b * G_GRAPHS];
    }
    __syncthreads();

#pragma unroll
    for (int it = 0; it < 4; ++it) {
      int u = it * 512 + tid;
      int r = u >> 6, cp = u & 63;
      const ushort_t* sp = xgb + (size_t)idxbuf[r] * D_DIM + cp * 8;
      short8 h = *reinterpret_cast<const short8*>(sp);
      int byteoff = r * 1024 + ((cp * 16) ^ ((r & 7) << 4));
      *reinterpret_cast<short8*>((char*)Ag + byteoff) = h;
    }
    __syncthreads();

    // L1: wave w -> cols [w*96, w*96+96) = 6 col tiles; 2 row tiles
    f32x4 acc[2][6];
#pragma unroll
    for (int i = 0; i < 2; ++i)
#pragma unroll
      for (int j = 0; j < 6; ++j) acc[i][j] = (f32x4){0.f, 0.f, 0.f, 0.f};

    const ushort_t* __restrict__ g1 =
        WG1 + (((size_t)b * 48 + w * 6) * 16) * 512 + (size_t)lane * 8;

    for (int ks = 0; ks < 16; ++ks) {
      short8 ah[2];
#pragma unroll
      for (int rt = 0; rt < 2; ++rt) {
        int R = rt * 16 + l15;
        int byteoff = R * 1024 + ((ks * 64 + lq * 16) ^ ((R & 7) << 4));
        ah[rt] = *reinterpret_cast<const short8*>((const char*)Ag + byteoff);
      }
#pragma unroll
      for (int ct = 0; ct < 6; ++ct) {
        short8 bh = *reinterpret_cast<const short8*>(g1 + (size_t)(ct * 16 + ks) * 512);
#pragma unroll
        for (int rt = 0; rt < 2; ++rt) {
          acc[rt][ct] = __builtin_amdgcn_mfma_f32_16x16x32_bf16(ah[rt], bh, acc[rt][ct], 0, 0, 0);
        }
      }
    }

    __syncthreads();  // reuse smem as hg (32 x 768 bf16, stride 1536B)
    ushort_t* hgs = (ushort_t*)smem;
#pragma unroll
    for (int ct = 0; ct < 6; ++ct) {
      int n = w * 96 + ct * 16 + l15;
      float bias = bg_shared[b * H_DIM + n];
#pragma unroll
      for (int rt = 0; rt < 2; ++rt) {
#pragma unroll
        for (int j = 0; j < 4; ++j) {
          int row = rt * 16 + lq * 4 + j;
          float v = fmaxf(acc[rt][ct][j] + bias, 0.0f);
          int byteoff = row * 1536 + ((n * 2) ^ ((row & 7) << 4));
          *reinterpret_cast<ushort_t*>((char*)hgs + byteoff) = rne_bf16(v);
        }
      }
    }
    __syncthreads();

    // L2: wave w -> o-tile w (16 cols); 2 row tiles; K=768
    f32x4 acc2[2];
    acc2[0] = (f32x4){0.f, 0.f, 0.f, 0.f};
    acc2[1] = (f32x4){0.f, 0.f, 0.f, 0.f};
    const ushort_t* __restrict__ g2 =
        WG2 + ((size_t)(b * 8 + w) * 24 * 64 + lane) * 8;

    for (int ks = 0; ks < 24; ++ks) {
      short8 b2 = *reinterpret_cast<const short8*>(g2 + (size_t)ks * 512);
#pragma unroll
      for (int rt = 0; rt < 2; ++rt) {
        int R = rt * 16 + l15;
        int byteoff = R * 1536 + ((ks * 64 + lq * 16) ^ ((R & 7) << 4));
        short8 a2 = *reinterpret_cast<const short8*>((const char*)hgs + byteoff);
        acc2[rt] = __builtin_amdgcn_mfma_f32_16x16x32_bf16(a2, b2, acc2[rt], 0, 0, 0);
      }
    }

    int o = w * 16 + l15;
    float bo = bg_head[b * 2 * GHD + o];
#pragma unroll
    for (int rt = 0; rt < 2; ++rt) {
#pragma unroll
      for (int j = 0; j < 4; ++j) {
        int r = rt * 16 + lq * 4 + j;
        if (base + r < gc) {
          int g = idxbuf[r];
          float v = acc2[rt][j] + bo;
          if (o < GHD) out[g * GHD + o] = v;
          else out[GV_OFF + g * GHD + (o - GHD)] = v * v;
        }
      }
    }
  }
}

// ---------------------------------------------------------------------------
extern "C" void kernel_launch(void* const* d_in, const int* in_sizes, int n_in,
                              void* d_out, int out_size, void* d_ws, size_t ws_size,
                              hipStream_t stream) {
  const float* x         = (const float*)d_in[0];
  const int*   batch     = (const int*)d_in[1];
  const int*   dsname    = (const int*)d_in[2];
  const float* Wg_shared = (const float*)d_in[3];
  const float* bg_shared = (const float*)d_in[4];
  const float* Wg_head   = (const float*)d_in[5];
  const float* bg_head   = (const float*)d_in[6];
  const float* Wn1       = (const float*)d_in[7];
  const float* bn1       = (const float*)d_in[8];
  const float* Wn2       = (const float*)d_in[9];
  const float* bn2       = (const float*)d_in[10];
  float* out = (float*)d_out;

  int* ws_i   = (int*)d_ws;
  int* cnt    = ws_i;               // 4
  int* gcnt   = ws_i + 8;           // 4
  int* pbase  = ws_i + 12;          // 4
  int* gstart = ws_i + 16;          // 1025 (ends 1041)
  int* poolflag = ws_i + 1044;      // 1
  int* goff   = ws_i + 1056;        // 1024
  int* glist  = ws_i + 2080;        // 4096
  int* lists  = ws_i + 6176;        // 4*32768 -> end 137248
  ushort_t* xgb  = (ushort_t*)(ws_i + 137248);  // 1024*512
  ushort_t* WPh  = xgb + 524288;                // 4*512*512
  ushort_t* W2T  = WPh + 1048576;               // 4*16*512
  ushort_t* WG1  = W2T + 32768;                 // 1572864
  ushort_t* WG2  = WG1 + 1572864;               // 393216

  hipMemsetAsync(poolflag, 0, sizeof(int), stream);
  segscan_kernel<<<1, 1024, 0, stream>>>(batch, dsname, gstart, goff, glist,
                                         cnt, gcnt, pbase);
  prep_kernel<<<776, 256, 0, stream>>>(gstart, goff, dsname, lists,
                                       Wn1, WPh, Wg_shared, WG1,
                                       Wg_head, WG2, Wn2, W2T);
  mega_kernel<<<POOL_BLOCKS + NODE_BLOCKS + GRAPH_BLOCKS, 512, 0, stream>>>(
      x, WPh, bn1, W2T, bn2, cnt, pbase, lists, gstart,
      xgb, poolflag, WG1, bg_shared, WG2, bg_head, gcnt, glist, out);
}

// Round 23
// 86.110 us; speedup vs baseline: 3.0484x; 3.0484x over previous
//
#include <hip/hip_runtime.h>

#define N_NODES 32768
#define G_GRAPHS 1024
#define D_DIM 512
#define H_DIM 768
#define B_BR 4
#define GHD 64
#define NHD 3

// output layout (f32, concatenated flat)
#define NH_OFF (G_GRAPHS * GHD)
#define GV_OFF (G_GRAPHS * GHD + N_NODES * NHD)
#define NV_OFF (2 * G_GRAPHS * GHD + N_NODES * NHD)

typedef unsigned short ushort_t;
typedef __attribute__((ext_vector_type(8))) short short8;
typedef __attribute__((ext_vector_type(4))) float f32x4;
typedef __attribute__((ext_vector_type(4))) ushort_t ushort4_t;

__device__ __forceinline__ ushort_t rne_bf16(float v) {
  unsigned bits = __float_as_uint(v);
  return (ushort_t)((bits + 0x7fffu + ((bits >> 16) & 1u)) >> 16);
}

// ---------------------------------------------------------------------------
// fused segment-bounds + 4-wave branch scan. One block, 1024 threads.
// ---------------------------------------------------------------------------
__global__ __launch_bounds__(1024) void segscan_kernel(
    const int* __restrict__ batch, const int* __restrict__ dsname,
    int* __restrict__ gstart, int* __restrict__ goff, int* __restrict__ glist,
    int* __restrict__ cnt, int* __restrict__ gcnt, int* __restrict__ pbase) {
  __shared__ int sg[G_GRAPHS + 1];
  __shared__ int scnt[4], sgcnt[4];
  const int tid = threadIdx.x;
  {
    int g = tid;
    int lo = 0, hi = N_NODES;
    while (lo < hi) { int mid = (lo + hi) >> 1; if (batch[mid] < g) lo = mid + 1; else hi = mid; }
    sg[g] = lo; gstart[g] = lo;
    if (tid == 0) { sg[G_GRAPHS] = N_NODES; gstart[G_GRAPHS] = N_NODES; }
  }
  __syncthreads();
  if (tid < 256) {
    const int lane = tid & 63;
    const int b = tid >> 6;
    int run_n = 0, run_g = 0;
    for (int c = 0; c < G_GRAPHS / 64; ++c) {
      int g = c * 64 + lane;
      int mine = (dsname[g] == b) ? 1 : 0;
      int len = mine ? (sg[g + 1] - sg[g]) : 0;
      int sl = len, so = mine;
#pragma unroll
      for (int off = 1; off < 64; off <<= 1) {
        int tl = __shfl_up(sl, off);
        int to = __shfl_up(so, off);
        if (lane >= off) { sl += tl; so += to; }
      }
      if (mine) {
        goff[g] = run_n + sl - len;
        glist[b * G_GRAPHS + run_g + so - 1] = g;
      }
      run_n += __shfl(sl, 63);
      run_g += __shfl(so, 63);
    }
    if (lane == 0) { scnt[b] = run_n; sgcnt[b] = run_g; }
  }
  __syncthreads();
  if (tid == 0) {
    int p = 0;
    for (int b2 = 0; b2 < 4; ++b2) {
      cnt[b2] = scnt[b2];
      gcnt[b2] = sgcnt[b2];
      pbase[b2] = p;
      p += (scnt[b2] + 63) & ~63;
    }
  }
}

// ---------------------------------------------------------------------------
// prep kernel (512 threads): pool (bid<1024, 1 graph/block, 8 row-stripes,
// pure streaming reduction) + lists emit + weight conv (1024..1671)
// ---------------------------------------------------------------------------
__global__ __launch_bounds__(512) void prep_kernel(
    const float* __restrict__ x, const int* __restrict__ batch,
    const int* __restrict__ dsname, const int* __restrict__ gstart,
    const int* __restrict__ goff,
    int* __restrict__ lists,
    ushort_t* __restrict__ xgb,
    const float* __restrict__ Wn1, ushort_t* __restrict__ WPh,
    const float* __restrict__ Wg1, ushort_t* __restrict__ WG1,
    const float* __restrict__ Wgh, ushort_t* __restrict__ WG2,
    const float* __restrict__ Wn2, ushort_t* __restrict__ W2T) {
  __shared__ float Ws[64][65];  // 16.6 KB (also used as [8][64][8] reduction)
  const int bid = blockIdx.x;
  const int tid = threadIdx.x;

  if (bid < 1024) {
    // pool: 1 graph per block. thread = (rl 0..7, cs 0..63). no in-loop stores.
    const int rl = tid >> 6;
    const int cs = tid & 63;
    const int g = bid;
    const int start = gstart[g];
    const int len = gstart[g + 1] - start;
    const int b = dsname[g];
    const int og = goff[g];
    for (int i = tid; i < len; i += 512) lists[b * N_NODES + og + i] = start + i;
    float s0 = 0.f, s1 = 0.f, s2 = 0.f, s3 = 0.f;
    float s4 = 0.f, s5 = 0.f, s6 = 0.f, s7 = 0.f;
    for (int i = rl; i < len; i += 8) {
      const float* sp = x + (size_t)(start + i) * D_DIM + cs * 8;
      float4 v0 = *reinterpret_cast<const float4*>(sp);
      float4 v1 = *reinterpret_cast<const float4*>(sp + 4);
      s0 += v0.x; s1 += v0.y; s2 += v0.z; s3 += v0.w;
      s4 += v1.x; s5 += v1.y; s6 += v1.z; s7 += v1.w;
    }
    float* red = (float*)Ws;  // [8][64][8] f32 = 16 KB
    float* rr = red + (rl * 64 + cs) * 8;
    rr[0] = s0; rr[1] = s1; rr[2] = s2; rr[3] = s3;
    rr[4] = s4; rr[5] = s5; rr[6] = s6; rr[7] = s7;
    __syncthreads();
    if (rl == 0) {
      float inv = (len > 0) ? 1.0f / (float)len : 0.0f;
      short8 h;
#pragma unroll
      for (int k = 0; k < 8; ++k) {
        float tot = 0.f;
#pragma unroll
        for (int p = 0; p < 8; ++p) tot += red[(p * 64 + cs) * 8 + k];
        h[k] = (short)rne_bf16(tot * inv);
      }
      *reinterpret_cast<short8*>(xgb + (size_t)g * D_DIM + cs * 8) = h;
    }
  } else {
    const int cid = bid - 1024;
    if (cid < 256) {  // Wn1 -> WPh
      int b = cid >> 6, t = cid & 63;
      int kt = t >> 3, nt = t & 7;
      const float* W = Wn1 + (size_t)b * D_DIM * D_DIM;
      for (int i = tid; i < 64 * 64; i += 512) {
        int k = i >> 6, n = i & 63;
        Ws[k][n] = W[(size_t)(kt * 64 + k) * D_DIM + nt * 64 + n];
      }
      __syncthreads();
      for (int i = tid; i < 64 * 8; i += 512) {
        int n = i >> 3, kq8 = i & 7;
        short8 sh;
#pragma unroll
        for (int j = 0; j < 8; ++j) sh[j] = (short)rne_bf16(Ws[kq8 * 8 + j][n]);
        int gn = nt * 64 + n, gk0 = kt * 64 + kq8 * 8;
        int n16 = gn >> 4, l15 = gn & 15;
        int ks = gk0 >> 5, lq = (gk0 >> 3) & 3;
        size_t off = ((((size_t)b * 32 + n16) * 16 + ks) * 64 + lq * 16 + l15) * 8;
        *reinterpret_cast<short8*>(WPh + off) = sh;
      }
    } else if (cid < 640) {  // Wg_shared -> WG1
      int l2 = cid - 256;
      int b = l2 / 96, t = l2 % 96;
      int kt = t / 12, nt = t % 12;
      const float* W = Wg1 + (size_t)b * D_DIM * H_DIM;
      for (int i = tid; i < 64 * 64; i += 512) {
        int k = i >> 6, n = i & 63;
        Ws[k][n] = W[(size_t)(kt * 64 + k) * H_DIM + nt * 64 + n];
      }
      __syncthreads();
      for (int i = tid; i < 64 * 8; i += 512) {
        int n = i >> 3, kq8 = i & 7;
        short8 sh;
#pragma unroll
        for (int j = 0; j < 8; ++j) sh[j] = (short)rne_bf16(Ws[kq8 * 8 + j][n]);
        int gn = nt * 64 + n, gk0 = kt * 64 + kq8 * 8;
        int n16 = gn >> 4, l15 = gn & 15;
        int ks = gk0 >> 5, lq = (gk0 >> 3) & 3;
        size_t off = ((((size_t)b * 48 + n16) * 16 + ks) * 64 + lq * 16 + l15) * 8;
        *reinterpret_cast<short8*>(WG1 + off) = sh;
      }
    } else if (cid < 644) {  // Wg_head -> WG2
      int b = cid - 640;
      const float* W = Wgh + (size_t)b * H_DIM * 2 * GHD;
      for (int i = tid; i < 8 * 24 * 64; i += 512) {
        int n16 = i / (24 * 64);
        int rem = i % (24 * 64);
        int ks = rem / 64, lane = rem % 64;
        int l15 = lane & 15, lq = lane >> 4;
        int o = n16 * 16 + l15;
        short8 sv;
#pragma unroll
        for (int j = 0; j < 8; ++j) {
          int k = ks * 32 + lq * 8 + j;
          sv[j] = (short)rne_bf16(W[(size_t)k * 128 + o]);
        }
        *reinterpret_cast<short8*>(WG2 + (size_t)i * 8 + (size_t)b * (8 * 24 * 64 * 8)) = sv;
      }
    } else {  // Wn2 -> W2T
      int b = cid - 644;
      for (int i = tid; i < 16 * D_DIM; i += 512) {
        int o = i & 15, c = i >> 4;
        float v = (o < 6) ? Wn2[(size_t)b * D_DIM * 6 + c * 6 + o] : 0.0f;
        W2T[(size_t)b * 16 * D_DIM + o * D_DIM + c] = rne_bf16(v);
      }
    }
  }
}

// ---------------------------------------------------------------------------
// mega kernel, branch->XCD pinning. blocks [0,128): graph MLP.
// blocks [128, 128+576): node GEMM. A staged by direct gather+convert from x
// (L3-warmed by prep) into XOR-swizzled LDS; B via 2-buffer per-wave DMA.
// ---------------------------------------------------------------------------
#define NBM 64
#define GRAPH_BLOCKS 128
#define NODE_BLOCKS 576

__global__ __launch_bounds__(512, 2) void mega_kernel(
    const float* __restrict__ x,
    const ushort_t* __restrict__ WPh,
    const float* __restrict__ bn1,
    const ushort_t* __restrict__ W2T, const float* __restrict__ bn2,
    const int* __restrict__ cnt, const int* __restrict__ pbase,
    const int* __restrict__ lists,
    const ushort_t* __restrict__ xgb,
    const ushort_t* __restrict__ WG1, const float* __restrict__ bg_shared,
    const ushort_t* __restrict__ WG2, const float* __restrict__ bg_head,
    const int* __restrict__ gcnt, const int* __restrict__ glist,
    float* __restrict__ out) {
  __shared__ __align__(16) char smem[131072];
  __shared__ int idxbuf[64];

  const int bid = blockIdx.x;
  const int tid = threadIdx.x;
  const int lane = tid & 63;
  const int w = tid >> 6;
  const int l15 = lane & 15;
  const int lq = lane >> 4;

  if (bid >= GRAPH_BLOCKS) {
    // ---------------- node path (XCD-pinned, B-pipelined) ----------------
    const int nb = bid - GRAPH_BLOCKS;
    const int b = (nb & 7) >> 1;                    // XCD pair -> branch
    const int tile = ((nb >> 3) << 1) | (nb & 1);   // within-branch tile
    const int count = cnt[b];
    const int base = tile * NBM;
    if (base >= count) return;

    ushort_t* Ah = (ushort_t*)smem;
    if (tid < NBM) {
      int r = base + tid;
      idxbuf[tid] = (r < count) ? lists[b * N_NODES + r] : lists[b * N_NODES];
    }
    __syncthreads();  // idxbuf visible

    // stage A: gather rows from x, convert f32->bf16, swizzled ds_write.
#pragma unroll
    for (int it = 0; it < 8; ++it) {
      int u = it * 512 + tid;
      int r = u >> 6, cp = u & 63;
      const float* sp = x + (size_t)idxbuf[r] * D_DIM + cp * 8;
      float4 v0 = *reinterpret_cast<const float4*>(sp);
      float4 v1 = *reinterpret_cast<const float4*>(sp + 4);
      short8 h;
      h[0] = (short)rne_bf16(v0.x); h[1] = (short)rne_bf16(v0.y);
      h[2] = (short)rne_bf16(v0.z); h[3] = (short)rne_bf16(v0.w);
      h[4] = (short)rne_bf16(v1.x); h[5] = (short)rne_bf16(v1.y);
      h[6] = (short)rne_bf16(v1.z); h[7] = (short)rne_bf16(v1.w);
      *reinterpret_cast<short8*>((char*)Ah + r * 1024 + ((cp ^ (r & 7)) << 4)) = h;
    }
    __syncthreads();

    const ushort_t* __restrict__ wph =
        WPh + (((size_t)b * 32 + w * 4) * 16) * 512 + (size_t)lane * 8;
    ushort_t* Bl = (ushort_t*)(smem + 65536 + w * 8192);  // wave-private 2x4KB

    // prologue: issue ks=0 into buf0
#pragma unroll
    for (int ct = 0; ct < 4; ++ct) {
      __builtin_amdgcn_global_load_lds(
          (const __attribute__((address_space(1))) void*)(wph + (size_t)(ct * 16) * 512),
          (__attribute__((address_space(3))) void*)(Bl + ct * 512),
          16, 0, 0);
    }

    f32x4 acc[4][4];
#pragma unroll
    for (int i = 0; i < 4; ++i)
#pragma unroll
      for (int j = 0; j < 4; ++j) acc[i][j] = (f32x4){0.f, 0.f, 0.f, 0.f};

#pragma unroll
    for (int ks = 0; ks < 16; ++ks) {
      const int nks = (ks + 1) & 15;
      ushort_t* Bnx = Bl + ((ks + 1) & 1) * 2048;
#pragma unroll
      for (int ct = 0; ct < 4; ++ct) {
        __builtin_amdgcn_global_load_lds(
            (const __attribute__((address_space(1))) void*)(wph + (size_t)(ct * 16 + nks) * 512),
            (__attribute__((address_space(3))) void*)(Bnx + ct * 512),
            16, 0, 0);
      }
      asm volatile("s_waitcnt vmcnt(4)" ::: "memory");
      __builtin_amdgcn_sched_barrier(0);
      const ushort_t* Bc = Bl + (ks & 1) * 2048;
      short8 ah[4], bh[4];
#pragma unroll
      for (int rt = 0; rt < 4; ++rt) {
        int R = rt * 16 + l15;
        int byteoff = R * 1024 + ((ks * 64 + lq * 16) ^ ((R & 7) << 4));
        ah[rt] = *reinterpret_cast<const short8*>((const char*)Ah + byteoff);
      }
#pragma unroll
      for (int ct = 0; ct < 4; ++ct)
        bh[ct] = *reinterpret_cast<const short8*>(Bc + ct * 512 + lane * 8);
#pragma unroll
      for (int ct = 0; ct < 4; ++ct) {
#pragma unroll
        for (int rt = 0; rt < 4; ++rt) {
          acc[rt][ct] = __builtin_amdgcn_mfma_f32_16x16x32_bf16(ah[rt], bh[ct], acc[rt][ct], 0, 0, 0);
        }
      }
    }

    __syncthreads();
    ushort_t* hn = Ah;
#pragma unroll
    for (int ct = 0; ct < 4; ++ct) {
      int n = w * 64 + ct * 16 + l15;
      float bias = bn1[b * D_DIM + n];
#pragma unroll
      for (int rt = 0; rt < 4; ++rt) {
#pragma unroll
        for (int j = 0; j < 4; ++j) {
          int row = rt * 16 + lq * 4 + j;
          float v = fmaxf(acc[rt][ct][j] + bias, 0.0f);
          int byteoff = row * 1024 + ((n * 2) ^ ((row & 7) << 4));
          *reinterpret_cast<ushort_t*>((char*)hn + byteoff) = rne_bf16(v);
        }
      }
    }
    __syncthreads();

    if (w < 4) {
      f32x4 acc2 = (f32x4){0.f, 0.f, 0.f, 0.f};
      const ushort_t* __restrict__ w2 =
          W2T + (size_t)b * (16 * 512) + (size_t)l15 * 512 + lq * 8;
      const int R = w * 16 + l15;
#pragma unroll
      for (int ks = 0; ks < 16; ++ks) {
        int byteoff = R * 1024 + ((ks * 64 + lq * 16) ^ ((R & 7) << 4));
        short8 a2 = *reinterpret_cast<const short8*>((const char*)hn + byteoff);
        short8 b2 = *reinterpret_cast<const short8*>(w2 + ks * 32);
        acc2 = __builtin_amdgcn_mfma_f32_16x16x32_bf16(a2, b2, acc2, 0, 0, 0);
      }
      int o = l15;
      if (o < 6) {
        float bo = bn2[b * 6 + o];
#pragma unroll
        for (int j = 0; j < 4; ++j) {
          int r = w * 16 + lq * 4 + j;
          if (base + r < count) {
            int n = idxbuf[r];
            float v = acc2[j] + bo;
            if (o < NHD) out[NH_OFF + n * NHD + o] = v;
            else out[NV_OFF + n * NHD + (o - NHD)] = v * v;
          }
        }
      }
    }
  } else {
    // ---------------- graph path (XCD-pinned) ----------------
    const int gb = bid;
    const int b = (gb & 7) >> 1;                    // XCD pair -> branch
    const int tile = ((gb >> 3) << 1) | (gb & 1);   // 0..31
    const int gc = gcnt[b];
    const int base = tile * 32;
    if (base >= gc) return;

    ushort_t* Ag = (ushort_t*)smem;       // 32 x 512 bf16, swizzled (32 KB)
    if (tid < 32) {
      int r = base + tid;
      idxbuf[tid] = (r < gc) ? glist[b * G_GRAPHS + r] : glist[b * G_GRAPHS];
    }
    __syncthreads();

#pragma unroll
    for (int it = 0; it < 4; ++it) {
      int u = it * 512 + tid;
      int r = u >> 6, cp = u & 63;
      const ushort_t* sp = xgb + (size_t)idxbuf[r] * D_DIM + cp * 8;
      short8 h = *reinterpret_cast<const short8*>(sp);
      int byteoff = r * 1024 + ((cp * 16) ^ ((r & 7) << 4));
      *reinterpret_cast<short8*>((char*)Ag + byteoff) = h;
    }
    __syncthreads();

    // L1: wave w -> cols [w*96, w*96+96) = 6 col tiles; 2 row tiles
    f32x4 acc[2][6];
#pragma unroll
    for (int i = 0; i < 2; ++i)
#pragma unroll
      for (int j = 0; j < 6; ++j) acc[i][j] = (f32x4){0.f, 0.f, 0.f, 0.f};

    const ushort_t* __restrict__ g1 =
        WG1 + (((size_t)b * 48 + w * 6) * 16) * 512 + (size_t)lane * 8;

    for (int ks = 0; ks < 16; ++ks) {
      short8 ah[2];
#pragma unroll
      for (int rt = 0; rt < 2; ++rt) {
        int R = rt * 16 + l15;
        int byteoff = R * 1024 + ((ks * 64 + lq * 16) ^ ((R & 7) << 4));
        ah[rt] = *reinterpret_cast<const short8*>((const char*)Ag + byteoff);
      }
#pragma unroll
      for (int ct = 0; ct < 6; ++ct) {
        short8 bh = *reinterpret_cast<const short8*>(g1 + (size_t)(ct * 16 + ks) * 512);
#pragma unroll
        for (int rt = 0; rt < 2; ++rt) {
          acc[rt][ct] = __builtin_amdgcn_mfma_f32_16x16x32_bf16(ah[rt], bh, acc[rt][ct], 0, 0, 0);
        }
      }
    }

    __syncthreads();  // reuse smem as hg (32 x 768 bf16, stride 1536B)
    ushort_t* hgs = (ushort_t*)smem;
#pragma unroll
    for (int ct = 0; ct < 6; ++ct) {
      int n = w * 96 + ct * 16 + l15;
      float bias = bg_shared[b * H_DIM + n];
#pragma unroll
      for (int rt = 0; rt < 2; ++rt) {
#pragma unroll
        for (int j = 0; j < 4; ++j) {
          int row = rt * 16 + lq * 4 + j;
          float v = fmaxf(acc[rt][ct][j] + bias, 0.0f);
          int byteoff = row * 1536 + ((n * 2) ^ ((row & 7) << 4));
          *reinterpret_cast<ushort_t*>((char*)hgs + byteoff) = rne_bf16(v);
        }
      }
    }
    __syncthreads();

    // L2: wave w -> o-tile w (16 cols); 2 row tiles; K=768
    f32x4 acc2[2];
    acc2[0] = (f32x4){0.f, 0.f, 0.f, 0.f};
    acc2[1] = (f32x4){0.f, 0.f, 0.f, 0.f};
    const ushort_t* __restrict__ g2 =
        WG2 + ((size_t)(b * 8 + w) * 24 * 64 + lane) * 8;

    for (int ks = 0; ks < 24; ++ks) {
      short8 b2 = *reinterpret_cast<const short8*>(g2 + (size_t)ks * 512);
#pragma unroll
      for (int rt = 0; rt < 2; ++rt) {
        int R = rt * 16 + l15;
        int byteoff = R * 1536 + ((ks * 64 + lq * 16) ^ ((R & 7) << 4));
        short8 a2 = *reinterpret_cast<const short8*>((const char*)hgs + byteoff);
        acc2[rt] = __builtin_amdgcn_mfma_f32_16x16x32_bf16(a2, b2, acc2[rt], 0, 0, 0);
      }
    }

    int o = w * 16 + l15;
    float bo = bg_head[b * 2 * GHD + o];
#pragma unroll
    for (int rt = 0; rt < 2; ++rt) {
#pragma unroll
      for (int j = 0; j < 4; ++j) {
        int r = rt * 16 + lq * 4 + j;
        if (base + r < gc) {
          int g = idxbuf[r];
          float v = acc2[rt][j] + bo;
          if (o < GHD) out[g * GHD + o] = v;
          else out[GV_OFF + g * GHD + (o - GHD)] = v * v;
        }
      }
    }
  }
}

// ---------------------------------------------------------------------------
extern "C" void kernel_launch(void* const* d_in, const int* in_sizes, int n_in,
                              void* d_out, int out_size, void* d_ws, size_t ws_size,
                              hipStream_t stream) {
  const float* x         = (const float*)d_in[0];
  const int*   batch     = (const int*)d_in[1];
  const int*   dsname    = (const int*)d_in[2];
  const float* Wg_shared = (const float*)d_in[3];
  const float* bg_shared = (const float*)d_in[4];
  const float* Wg_head   = (const float*)d_in[5];
  const float* bg_head   = (const float*)d_in[6];
  const float* Wn1       = (const float*)d_in[7];
  const float* bn1       = (const float*)d_in[8];
  const float* Wn2       = (const float*)d_in[9];
  const float* bn2       = (const float*)d_in[10];
  float* out = (float*)d_out;

  int* ws_i   = (int*)d_ws;
  int* cnt    = ws_i;               // 4
  int* gcnt   = ws_i + 8;           // 4
  int* pbase  = ws_i + 12;          // 4
  int* gstart = ws_i + 16;          // 1025
  int* goff   = ws_i + 1056;        // 1024
  int* glist  = ws_i + 2080;        // 4096
  int* lists  = ws_i + 6176;        // 4*32768 -> end 137248
  ushort_t* xgb  = (ushort_t*)(ws_i + 137248);  // 1024*512
  ushort_t* WPh  = xgb + 524288;                // 4*512*512
  ushort_t* W2T  = WPh + 1048576;               // 4*16*512
  ushort_t* WG1  = W2T + 32768;                 // 1572864
  ushort_t* WG2  = WG1 + 1572864;               // 393216

  segscan_kernel<<<1, 1024, 0, stream>>>(batch, dsname, gstart, goff, glist,
                                         cnt, gcnt, pbase);
  prep_kernel<<<1672, 512, 0, stream>>>(x, batch, dsname, gstart, goff,
                                        lists, xgb,
                                        Wn1, WPh, Wg_shared, WG1,
                                        Wg_head, WG2, Wn2, W2T);
  mega_kernel<<<GRAPH_BLOCKS + NODE_BLOCKS, 512, 0, stream>>>(
      x, WPh, bn1, W2T, bn2, cnt, pbase, lists,
      xgb, WG1, bg_shared, WG2, bg_head, gcnt, glist, out);
}